// Round 1
// baseline (61.001 us; speedup 1.0000x reference)
//
#include <hip/hip_runtime.h>
#include <math.h>

#define BB 8
#define HH 480
#define WW 640
#define CC 5
#define HW (HH * WW)

// stats layout (doubles in d_ws):
// [0]              : global L1 sum (sum |pred_m - gt_m| over b,c,h,w)
// [1 .. 8]         : per-b mask sum (sum of combined_mask over h,w; same for all c)
// [9 .. 9+200)     : per (b,c) stats: idx = 9 + b*25 + c*5 + k
//                    k: 0=sum(pm) 1=sum(gm) 2=sum(pm*gm) 3=sum(pm*pm) 4=sum(gm*gm)
#define NSTATS 209
#define GRAY2_OFFSET 4096  // bytes into d_ws where gray2 buffer starts

__global__ void k_zero_stats(double* __restrict__ stats) {
    int i = threadIdx.x;
    if (i < NSTATS) stats[i] = 0.0;
}

__global__ void k_gray2(const float* __restrict__ img2, float* __restrict__ gray2) {
    int idx = blockIdx.x * blockDim.x + threadIdx.x;
    if (idx >= BB * HW) return;
    int b = idx / HW;
    int p = idx - b * HW;
    const float* base = img2 + (size_t)b * 3 * HW + p;
    float g = 0.299f * base[0] + 0.587f * base[HW] + 0.114f * base[2 * HW];
    gray2[idx] = g;
}

__global__ __launch_bounds__(256) void k_main(
    const float* __restrict__ img1, const float* __restrict__ flow,
    const float* __restrict__ ev, const float* __restrict__ vmask,
    const float* __restrict__ gray2, float* __restrict__ pred_out,
    double* __restrict__ stats)
{
    const int b = blockIdx.y;
    const float* i1  = img1  + (size_t)b * 3 * HW;
    const float* fl  = flow  + (size_t)b * 2 * HW;
    const float* evb = ev    + (size_t)b * CC * HW;
    const float* vm  = vmask + (size_t)b * HW;
    const float* g2  = gray2 + (size_t)b * HW;
    float* po = pred_out + (size_t)b * CC * HW;

    // acc[0]=l1, acc[1]=masksum, acc[2 + c*5 + k] = per-channel stats
    float acc[27];
#pragma unroll
    for (int i = 0; i < 27; ++i) acc[i] = 0.0f;

    const int stride = gridDim.x * blockDim.x;
    for (int p = blockIdx.x * blockDim.x + threadIdx.x; p < HW; p += stride) {
        int py = p / WW;
        int px = p - py * WW;

        float g1 = 0.299f * i1[p] + 0.587f * i1[p + HW] + 0.114f * i1[p + 2 * HW];
        float fx = fl[p];
        float fy = fl[p + HW];

        // bilinear warp of gray2, zeros padding
        float x = (float)px + fx;
        float y = (float)py + fy;
        float x0f = floorf(x);
        float y0f = floorf(y);
        float wx = x - x0f;
        float wy = y - y0f;
        int x0 = (int)x0f;
        int y0 = (int)y0f;
        int x1 = x0 + 1;
        int y1 = y0 + 1;

        float t00 = 0.0f, t10 = 0.0f, t01 = 0.0f, t11 = 0.0f;
        bool xin0 = (x0 >= 0) & (x0 < WW);
        bool xin1 = (x1 >= 0) & (x1 < WW);
        bool yin0 = (y0 >= 0) & (y0 < HH);
        bool yin1 = (y1 >= 0) & (y1 < HH);
        if (yin0) {
            if (xin0) t00 = g2[y0 * WW + x0];
            if (xin1) t10 = g2[y0 * WW + x1];
        }
        if (yin1) {
            if (xin0) t01 = g2[y1 * WW + x0];
            if (xin1) t11 = g2[y1 * WW + x1];
        }
        float warp = t00 * (1.0f - wx) * (1.0f - wy)
                   + t10 * wx * (1.0f - wy)
                   + t01 * (1.0f - wx) * wy
                   + t11 * wx * wy;

        float nc = tanhf((warp - g1) * 5.0f);
        float pos = fmaxf(nc, 0.0f);
        float neg = fmaxf(-nc, 0.0f);

        float pr[CC];
        pr[0] = pos;
        pr[1] = neg;
        pr[2] = 0.25f * pos + 0.75f * neg;
        pr[3] = 0.50f * pos + 0.50f * neg;
        pr[4] = 0.75f * pos + 0.25f * neg;

        float m = ((fx * fx + fy * fy) > 0.01f) ? vm[p] : 0.0f;
        acc[1] += m;

#pragma unroll
        for (int c = 0; c < CC; ++c) {
            po[c * HW + p] = pr[c];
            float g  = evb[c * HW + p];
            float pm = pr[c] * m;
            float gm = g * m;
            acc[0] += fabsf(pm - gm);
            acc[2 + c * 5 + 0] += pm;
            acc[2 + c * 5 + 1] += gm;
            acc[2 + c * 5 + 2] += pm * gm;
            acc[2 + c * 5 + 3] += pm * pm;
            acc[2 + c * 5 + 4] += gm * gm;
        }
    }

    // wave (64-lane) reduce each accumulator
#pragma unroll
    for (int i = 0; i < 27; ++i) {
        float v = acc[i];
        for (int off = 32; off > 0; off >>= 1) v += __shfl_down(v, off, 64);
        acc[i] = v;
    }

    __shared__ float sdata[4][27];
    int lane = threadIdx.x & 63;
    int wid  = threadIdx.x >> 6;
    if (lane == 0) {
#pragma unroll
        for (int i = 0; i < 27; ++i) sdata[wid][i] = acc[i];
    }
    __syncthreads();

    if (threadIdx.x < 27) {
        int i = threadIdx.x;
        float s = sdata[0][i] + sdata[1][i] + sdata[2][i] + sdata[3][i];
        double* dst;
        if (i == 0)      dst = &stats[0];
        else if (i == 1) dst = &stats[1 + b];
        else             dst = &stats[9 + b * 25 + (i - 2)];
        atomicAdd(dst, (double)s);
    }
}

__global__ void k_final(const double* __restrict__ stats, float* __restrict__ out) {
    int t = threadIdx.x;  // 64 threads
    double contrib = 0.0;
    if (t < BB * CC) {
        int b = t / CC;
        int c = t - b * CC;
        const double* s = stats + 9 + b * 25 + c * 5;
        double Sp = s[0], Sg = s[1], Spg = s[2], Spp = s[3], Sgg = s[4];
        const double N = (double)HW;
        double num  = Spg - Sp * Sg / N;
        double varp = Spp - Sp * Sp / N; if (varp < 0.0) varp = 0.0;
        double varg = Sgg - Sg * Sg / N; if (varg < 0.0) varg = 0.0;
        double den  = sqrt(varp) * sqrt(varg) + 1e-6;
        double corr = num / den;
        bool valid = stats[1 + b] > 0.0;
        contrib = valid ? (1.0 - corr) : 0.0;
    }
    for (int off = 32; off > 0; off >>= 1) contrib += __shfl_down(contrib, off, 64);
    if (t == 0) {
        double msum_total = 0.0;
        for (int b = 0; b < BB; ++b) msum_total += stats[1 + b];
        double mask_sum = (double)CC * msum_total + 1e-6;
        double l1_loss = stats[0] / mask_sum;
        double corr_loss = contrib / (double)(BB * CC);
        out[0] = (float)(l1_loss + 0.5 * corr_loss);
    }
}

extern "C" void kernel_launch(void* const* d_in, const int* in_sizes, int n_in,
                              void* d_out, int out_size, void* d_ws, size_t ws_size,
                              hipStream_t stream) {
    const float* img1  = (const float*)d_in[0];
    const float* img2  = (const float*)d_in[1];
    const float* flow  = (const float*)d_in[2];
    const float* ev    = (const float*)d_in[3];
    const float* vmask = (const float*)d_in[4];
    float* out = (float*)d_out;

    double* stats = (double*)d_ws;
    float* gray2  = (float*)((char*)d_ws + GRAY2_OFFSET);

    k_zero_stats<<<1, 256, 0, stream>>>(stats);

    int total = BB * HW;
    k_gray2<<<(total + 255) / 256, 256, 0, stream>>>(img2, gray2);

    dim3 grid(150, BB);  // 150*256 = 38400 threads/image; 307200/38400 = 8 px/thread
    k_main<<<grid, 256, 0, stream>>>(img1, flow, ev, vmask, gray2, out + 1, stats);

    k_final<<<1, 64, 0, stream>>>(stats, out);
}